// Round 1
// baseline (234.861 us; speedup 1.0000x reference)
//
#include <hip/hip_runtime.h>
#include <hip/hip_bf16.h>

// Problem: B=64, L=256, D=1024, F=1024 (all fp32)
//   A = X @ W0, C = X @ W1  (X = input as [B*L, D])
//   per (b,f): h1 = max-prefix of a over l; h2 = max_t(h1_{t-1} + c_t); out = tanh(h2 + bias)
//
// Plan: cast X/W to bf16 (RNE), W transposed to [F,D] so A/B stage identically,
// m97-style 128x128 MFMA GEMM writes A,C fp32 to ws, then a coalesced scan kernel.

#define GLOBAL_AS __attribute__((address_space(1)))
#define LDS_AS __attribute__((address_space(3)))

typedef short bf16x8 __attribute__((ext_vector_type(8)));
typedef float floatx4 __attribute__((ext_vector_type(4)));

__device__ __forceinline__ unsigned short f2bf(float f) {
    union { float f; unsigned u; } x; x.f = f;
    unsigned r = x.u + 0x7fffu + ((x.u >> 16) & 1u);   // round-to-nearest-even
    return (unsigned short)(r >> 16);
}

__device__ __forceinline__ void async_copy16(const void* g, void* l) {
    __builtin_amdgcn_global_load_lds((GLOBAL_AS void*)g, (LDS_AS void*)l, 16, 0, 0);
}

// ---- X fp32 -> bf16 (16.7M elems, 4 per thread) --------------------------
__global__ __launch_bounds__(256) void cvt_x(const float4* __restrict__ in,
                                             ushort4* __restrict__ out) {
    int i = blockIdx.x * 256 + threadIdx.x;
    float4 v = in[i];
    ushort4 o;
    o.x = f2bf(v.x); o.y = f2bf(v.y); o.z = f2bf(v.z); o.w = f2bf(v.w);
    out[i] = o;
}

// ---- W [K=1024][N=1024] fp32 -> Wt [N][K] bf16 (tiled transpose) ---------
__global__ __launch_bounds__(256) void transpose_cvt(const float* __restrict__ W0,
                                                     const float* __restrict__ W1,
                                                     unsigned short* __restrict__ W0t,
                                                     unsigned short* __restrict__ W1t) {
    const float* W = blockIdx.z ? W1 : W0;
    unsigned short* Wt = blockIdx.z ? W1t : W0t;
    __shared__ unsigned short tile[32][33];
    int tx = threadIdx.x, ty = threadIdx.y;     // block (32,8)
    int n0 = blockIdx.x * 32, k0 = blockIdx.y * 32;
    #pragma unroll
    for (int j = 0; j < 32; j += 8)
        tile[ty + j][tx] = f2bf(W[(size_t)(k0 + ty + j) * 1024 + n0 + tx]);
    __syncthreads();
    #pragma unroll
    for (int j = 0; j < 32; j += 8)
        Wt[(size_t)(n0 + ty + j) * 1024 + k0 + tx] = tile[tx][ty + j];
}

// ---- GEMM: [16384,1024] x [1024,1024]^T -> fp32, dual output -------------
// grid (128, 16): y<8 -> W0t->A, y>=8 -> W1t->C. 128x128 tile, BK=32,
// 4 waves, each wave 64x64 via 4x4 of 16x16x32 MFMA. global_load_lds w=16.
__global__ __launch_bounds__(256) void gemm_dual(const unsigned short* __restrict__ Xbf,
                                                 const unsigned short* __restrict__ W0t,
                                                 const unsigned short* __restrict__ W1t,
                                                 float* __restrict__ A,
                                                 float* __restrict__ C) {
    constexpr int K = 1024, N = 1024;
    __shared__ unsigned short As[128 * 32];
    __shared__ unsigned short Bs[128 * 32];
    int t = threadIdx.x;
    int lane = t & 63, wave = t >> 6;
    int yt = blockIdx.y;
    const unsigned short* Wt = (yt < 8) ? W0t : W1t;
    float* Out = (yt < 8) ? A : C;
    int n0 = (yt & 7) * 128;
    size_t m0 = (size_t)blockIdx.x * 128;

    // staging: thread t -> row t>>2 (0..63), kcol (t&3)*8; LDS offset t*16B (lane-contiguous)
    const unsigned short* gA = Xbf + (m0 + (size_t)(t >> 2)) * K + (t & 3) * 8;
    const unsigned short* gB = Wt + ((size_t)n0 + (t >> 2)) * K + (t & 3) * 8;

    floatx4 acc[4][4] = {};
    int wm = (wave >> 1) * 64, wn = (wave & 1) * 64;
    int mrow = lane & 15;          // A m-row / B n-row / C col
    int kg = (lane >> 4) * 8;      // k-group within BK=32

    for (int k0 = 0; k0 < K; k0 += 32) {
        __syncthreads();
        async_copy16(gA + k0,            &As[t * 8]);
        async_copy16(gA + 64 * K + k0,   &As[2048 + t * 8]);
        async_copy16(gB + k0,            &Bs[t * 8]);
        async_copy16(gB + 64 * K + k0,   &Bs[2048 + t * 8]);
        __syncthreads();

        bf16x8 af[4], bfr[4];
        #pragma unroll
        for (int i = 0; i < 4; i++)
            af[i] = *(const bf16x8*)&As[(wm + i * 16 + mrow) * 32 + kg];
        #pragma unroll
        for (int j = 0; j < 4; j++)
            bfr[j] = *(const bf16x8*)&Bs[(wn + j * 16 + mrow) * 32 + kg];
        #pragma unroll
        for (int i = 0; i < 4; i++)
            #pragma unroll
            for (int j = 0; j < 4; j++)
                acc[i][j] = __builtin_amdgcn_mfma_f32_16x16x32_bf16(af[i], bfr[j], acc[i][j], 0, 0, 0);
    }

    // C/D layout: col = lane&15, row = (lane>>4)*4 + reg  [m89/m91 verified]
    int rbase = (lane >> 4) * 4;
    #pragma unroll
    for (int i = 0; i < 4; i++)
        #pragma unroll
        for (int j = 0; j < 4; j++)
            #pragma unroll
            for (int r = 0; r < 4; r++) {
                size_t row = m0 + wm + i * 16 + rbase + r;
                int col = n0 + wn + j * 16 + mrow;
                Out[row * N + col] = acc[i][j][r];
            }
}

// ---- scan over l per (b,f) -----------------------------------------------
// grid (64,4), block 256: f = by*256 + tid; stride-1024 loads are coalesced
// across the block (256 consecutive f per l-step).
__global__ __launch_bounds__(256) void scan_kernel(const float* __restrict__ A,
                                                   const float* __restrict__ Cc,
                                                   const float* __restrict__ bias,
                                                   float* __restrict__ out) {
    int b = blockIdx.x;
    int f = blockIdx.y * 256 + threadIdx.x;
    const float* ap = A + (size_t)b * 256 * 1024 + f;
    const float* cp = Cc + (size_t)b * 256 * 1024 + f;
    float h1 = 0.f, h2 = 0.f;
    #pragma unroll 8
    for (int l = 0; l < 256; l++) {
        float a = ap[(size_t)l * 1024];
        float c = cp[(size_t)l * 1024];
        h2 = fmaxf(h2, h1 + c);   // uses OLD h1 (reference ordering)
        h1 = fmaxf(h1, a);
    }
    out[b * 1024 + f] = tanhf(h2 + bias[f]);
}

extern "C" void kernel_launch(void* const* d_in, const int* in_sizes, int n_in,
                              void* d_out, int out_size, void* d_ws, size_t ws_size,
                              hipStream_t stream) {
    const float* X    = (const float*)d_in[0];  // [64,256,1024]
    const float* W0   = (const float*)d_in[1];  // [1024,1024]
    const float* W1   = (const float*)d_in[2];  // [1024,1024]
    const float* bias = (const float*)d_in[3];  // [1024]
    float* out = (float*)d_out;                 // [64,1024]

    char* ws = (char*)d_ws;
    unsigned short* Xbf = (unsigned short*)(ws);               // 32 MB
    unsigned short* W0t = (unsigned short*)(ws + 33554432);    // 2 MB
    unsigned short* W1t = (unsigned short*)(ws + 35651584);    // 2 MB
    float* A  = (float*)(ws + 37748736);                       // 64 MB
    float* Cc = (float*)(ws + 104857600);                      // 64 MB

    cvt_x<<<dim3(16384), dim3(256), 0, stream>>>((const float4*)X, (ushort4*)Xbf);
    transpose_cvt<<<dim3(32, 32, 2), dim3(32, 8), 0, stream>>>(W0, W1, W0t, W1t);
    gemm_dual<<<dim3(128, 16), dim3(256), 0, stream>>>(Xbf, W0t, W1t, A, Cc);
    scan_kernel<<<dim3(64, 4), dim3(256), 0, stream>>>(A, Cc, bias, out);
}

// Round 2
// 178.586 us; speedup vs baseline: 1.3151x; 1.3151x over previous
//
#include <hip/hip_runtime.h>
#include <hip/hip_bf16.h>

// B=64, L=256, D=1024, F=1024 (fp32).
//   A = X @ W0, C = X @ W1  (X as [16384, 1024])
//   per (b,f): h1 = max-prefix of a; h2 = max_t(h1_{t-1}+c_t); out = tanh(h2+bias)
//
// Max-plus decomposition: segment summary (A,C,AC) with combine
//   AC12 = max(AC1, AC2, A1+C2); A12=max(A1,A2); C12=max(C1,C2)
// lets each 128-row GEMM tile (= 128 contiguous l of one b) reduce to 3 floats/f.
// Fused kernel computes BOTH GEMMs per tile (dual acc: a,c for same (row,col)
// live in the same lane regs) and emits partials; finalize combines 2 halves.

#define GLOBAL_AS __attribute__((address_space(1)))
#define LDS_AS __attribute__((address_space(3)))

typedef short bf16x8 __attribute__((ext_vector_type(8)));
typedef float floatx4 __attribute__((ext_vector_type(4)));

__device__ __forceinline__ unsigned short f2bf(float f) {
    union { float f; unsigned u; } x; x.f = f;
    unsigned r = x.u + 0x7fffu + ((x.u >> 16) & 1u);   // RNE
    return (unsigned short)(r >> 16);
}

__device__ __forceinline__ void async_copy16(const void* g, void* l) {
    __builtin_amdgcn_global_load_lds((GLOBAL_AS void*)g, (LDS_AS void*)l, 16, 0, 0);
}

struct Seg { float A, C, AC; };

__device__ __forceinline__ Seg segCombine(const Seg& x, const Seg& y) {   // x precedes y in l
    Seg r;
    r.AC = fmaxf(fmaxf(x.AC, y.AC), x.A + y.C);
    r.A  = fmaxf(x.A, y.A);
    r.C  = fmaxf(x.C, y.C);
    return r;
}

__device__ __forceinline__ Seg segShflDown(const Seg& s, int d) {
    Seg r;
    r.A  = __shfl_down(s.A,  d, 64);
    r.C  = __shfl_down(s.C,  d, 64);
    r.AC = __shfl_down(s.AC, d, 64);
    return r;
}

// ---- X fp32 -> bf16 ------------------------------------------------------
__global__ __launch_bounds__(256) void cvt_x(const float4* __restrict__ in,
                                             ushort4* __restrict__ out) {
    int i = blockIdx.x * 256 + threadIdx.x;
    float4 v = in[i];
    ushort4 o;
    o.x = f2bf(v.x); o.y = f2bf(v.y); o.z = f2bf(v.z); o.w = f2bf(v.w);
    out[i] = o;
}

// ---- W [K][N] fp32 -> Wt [N][K] bf16 -------------------------------------
__global__ __launch_bounds__(256) void transpose_cvt(const float* __restrict__ W0,
                                                     const float* __restrict__ W1,
                                                     unsigned short* __restrict__ W0t,
                                                     unsigned short* __restrict__ W1t) {
    const float* W = blockIdx.z ? W1 : W0;
    unsigned short* Wt = blockIdx.z ? W1t : W0t;
    __shared__ unsigned short tile[32][33];
    int tx = threadIdx.x, ty = threadIdx.y;     // block (32,8)
    int n0 = blockIdx.x * 32, k0 = blockIdx.y * 32;
    #pragma unroll
    for (int j = 0; j < 32; j += 8)
        tile[ty + j][tx] = f2bf(W[(size_t)(k0 + ty + j) * 1024 + n0 + tx]);
    __syncthreads();
    #pragma unroll
    for (int j = 0; j < 32; j += 8)
        Wt[(size_t)(n0 + ty + j) * 1024 + k0 + tx] = tile[tx][ty + j];
}

// ---- Fused dual-GEMM + segment-scan --------------------------------------
// grid (128 m-tiles, 8 n-tiles), 256 threads (4 waves), each wave 64x64 dual.
__global__ __launch_bounds__(256, 2) void gemm_scan(const unsigned short* __restrict__ Xbf,
                                                    const unsigned short* __restrict__ W0t,
                                                    const unsigned short* __restrict__ W1t,
                                                    float* __restrict__ PA,
                                                    float* __restrict__ PC,
                                                    float* __restrict__ PAC) {
    constexpr int K = 1024;
    __shared__ unsigned short As[128 * 32];
    __shared__ unsigned short Bs0[128 * 32];
    __shared__ unsigned short Bs1[128 * 32];
    __shared__ float sumBuf[128][2][3];

    int t = threadIdx.x;
    int lane = t & 63, wave = t >> 6;
    int n0 = blockIdx.y * 128;
    size_t m0 = (size_t)blockIdx.x * 128;

    const unsigned short* gA  = Xbf + (m0 + (size_t)(t >> 2)) * K + (t & 3) * 8;
    const unsigned short* gB0 = W0t + ((size_t)n0 + (t >> 2)) * K + (t & 3) * 8;
    const unsigned short* gB1 = W1t + ((size_t)n0 + (t >> 2)) * K + (t & 3) * 8;

    floatx4 acc0[4][4] = {};   // X@W0 -> a
    floatx4 acc1[4][4] = {};   // X@W1 -> c
    int wm = (wave >> 1) * 64, wn = (wave & 1) * 64;
    int mrow = lane & 15;          // A m-row / B n-row / C col
    int kg = (lane >> 4) * 8;      // k-group within BK=32

    for (int k0 = 0; k0 < K; k0 += 32) {
        __syncthreads();
        async_copy16(gA  + k0,          &As[t * 8]);
        async_copy16(gA  + 64 * K + k0, &As[2048 + t * 8]);
        async_copy16(gB0 + k0,          &Bs0[t * 8]);
        async_copy16(gB0 + 64 * K + k0, &Bs0[2048 + t * 8]);
        async_copy16(gB1 + k0,          &Bs1[t * 8]);
        async_copy16(gB1 + 64 * K + k0, &Bs1[2048 + t * 8]);
        __syncthreads();

        bf16x8 af[4], b0[4], b1[4];
        #pragma unroll
        for (int i = 0; i < 4; i++)
            af[i] = *(const bf16x8*)&As[(wm + i * 16 + mrow) * 32 + kg];
        #pragma unroll
        for (int j = 0; j < 4; j++) {
            b0[j] = *(const bf16x8*)&Bs0[(wn + j * 16 + mrow) * 32 + kg];
            b1[j] = *(const bf16x8*)&Bs1[(wn + j * 16 + mrow) * 32 + kg];
        }
        #pragma unroll
        for (int i = 0; i < 4; i++)
            #pragma unroll
            for (int j = 0; j < 4; j++) {
                acc0[i][j] = __builtin_amdgcn_mfma_f32_16x16x32_bf16(af[i], b0[j], acc0[i][j], 0, 0, 0);
                acc1[i][j] = __builtin_amdgcn_mfma_f32_16x16x32_bf16(af[i], b1[j], acc1[i][j], 0, 0, 0);
            }
    }

    // ---- in-register scan reduction ----
    // C/D layout: col = lane&15, row = (lane>>4)*4 + reg  -> lane owns rows
    // i*16 + q*4 + r (q = lane>>4): order is (i, q, r) lexicographic in l.
    const float NEG = -1e30f;
    int q = lane >> 4;
    #pragma unroll
    for (int j = 0; j < 4; j++) {
        Seg S[4];
        #pragma unroll
        for (int i = 0; i < 4; i++) {
            float run = NEG, Cm = NEG, ACm = NEG;
            #pragma unroll
            for (int r = 0; r < 4; r++) {
                float c = acc1[i][j][r];
                ACm = fmaxf(ACm, run + c);
                Cm  = fmaxf(Cm, c);
                run = fmaxf(run, acc0[i][j][r]);
            }
            S[i].A = run; S[i].C = Cm; S[i].AC = ACm;
        }
        // combine across q (ordered): valid at lanes 0..15 after two steps
        #pragma unroll
        for (int i = 0; i < 4; i++) S[i] = segCombine(S[i], segShflDown(S[i], 16));
        #pragma unroll
        for (int i = 0; i < 4; i++) S[i] = segCombine(S[i], segShflDown(S[i], 32));
        // combine across i (in-lane, ordered)
        Seg W = S[0];
        #pragma unroll
        for (int i = 1; i < 4; i++) W = segCombine(W, S[i]);
        if (lane < 16) {
            int col = wn + j * 16 + lane;
            int half = wave >> 1;          // wm/64: rows 0-63 vs 64-127
            sumBuf[col][half][0] = W.A;
            sumBuf[col][half][1] = W.C;
            sumBuf[col][half][2] = W.AC;
        }
    }
    __syncthreads();
    if (t < 128) {
        Seg x0, x1;
        x0.A = sumBuf[t][0][0]; x0.C = sumBuf[t][0][1]; x0.AC = sumBuf[t][0][2];
        x1.A = sumBuf[t][1][0]; x1.C = sumBuf[t][1][1]; x1.AC = sumBuf[t][1][2];
        Seg Wt = segCombine(x0, x1);
        size_t idx = (size_t)blockIdx.x * 1024 + n0 + t;
        PA[idx] = Wt.A; PC[idx] = Wt.C; PAC[idx] = Wt.AC;
    }
}

// ---- finalize: combine the two 128-l halves per b, tanh + bias -----------
__global__ __launch_bounds__(256) void finalize(const float* __restrict__ PA,
                                                const float* __restrict__ PC,
                                                const float* __restrict__ PAC,
                                                const float* __restrict__ bias,
                                                float* __restrict__ out) {
    int b = blockIdx.x;
    int f = blockIdx.y * 256 + threadIdx.x;
    size_t i0 = (size_t)(2 * b) * 1024 + f;
    size_t i1 = (size_t)(2 * b + 1) * 1024 + f;
    Seg x0, x1;
    x0.A = PA[i0]; x0.C = PC[i0]; x0.AC = PAC[i0];
    x1.A = PA[i1]; x1.C = PC[i1]; x1.AC = PAC[i1];
    Seg w = segCombine(x0, x1);
    float h2 = fmaxf(0.f, fmaxf(w.C, w.AC));
    out[b * 1024 + f] = tanhf(h2 + bias[f]);
}

extern "C" void kernel_launch(void* const* d_in, const int* in_sizes, int n_in,
                              void* d_out, int out_size, void* d_ws, size_t ws_size,
                              hipStream_t stream) {
    const float* X    = (const float*)d_in[0];  // [64,256,1024]
    const float* W0   = (const float*)d_in[1];  // [1024,1024]
    const float* W1   = (const float*)d_in[2];  // [1024,1024]
    const float* bias = (const float*)d_in[3];  // [1024]
    float* out = (float*)d_out;                 // [64,1024]

    char* ws = (char*)d_ws;
    unsigned short* Xbf = (unsigned short*)(ws);               // 32 MB
    unsigned short* W0t = (unsigned short*)(ws + 33554432);    // 2 MB
    unsigned short* W1t = (unsigned short*)(ws + 35651584);    // 2 MB
    float* PA  = (float*)(ws + 37748736);                      // 512 KB
    float* PC  = (float*)(ws + 38273024);                      // 512 KB
    float* PAC = (float*)(ws + 38797312);                      // 512 KB

    cvt_x<<<dim3(16384), dim3(256), 0, stream>>>((const float4*)X, (ushort4*)Xbf);
    transpose_cvt<<<dim3(32, 32, 2), dim3(32, 8), 0, stream>>>(W0, W1, W0t, W1t);
    gemm_scan<<<dim3(128, 8), dim3(256), 0, stream>>>(Xbf, W0t, W1t, PA, PC, PAC);
    finalize<<<dim3(64, 4), dim3(256), 0, stream>>>(PA, PC, PAC, bias, out);
}